// Round 8
// baseline (277.891 us; speedup 1.0000x reference)
//
#include <hip/hip_runtime.h>

// 3-NN IDW upsampling, round 8: wave-uniform grid-culled brute force.
// k_qsort (grid=2): Morton-sort query indices per batch (any permutation is
//   correctness-neutral; Morton gives wave-compact query groups).
// k_knn (256 blocks x 256 thr, 1/CU): per-block LDS sparse-grid build
//   (verbatim round 7), then each wave autonomously serves 32 sorted queries
//   (2 lanes/query): bbox of the wave's home cells -> ring expansion over
//   wave-uniform row segments -> EVERY lane scans every candidate point
//   (broadcast LDS reads, zero divergence), pair-split even/odd.
//   Validated packed-key med3 top-4 per lane -> 8 candidates/query ->
//   exact-f64 re-rank + f64 IDW epilogue (identical arithmetic to rounds 1-7).

constexpr int   B  = 2;
constexpr int   S  = 4096;
constexpr int   NQ = 16384;
constexpr int   G  = 16;
constexpr int   NC = G * G * G;
constexpr float LOF  = -4.25f;
constexpr float W    = 0.53125f;          // 8.5 / 16
constexpr float INVW = 1.0f / W;

constexpr int THREADS = 256;
constexpr int PPT     = S / THREADS;      // 16 sparse points per thread (build)
constexpr int QPW     = 32;               // queries per wave (2 lanes each)
constexpr int QPB     = 4 * QPW;          // 128 queries per block

__device__ __forceinline__ unsigned med3u(unsigned a, unsigned b, unsigned c) {
    unsigned d;
    asm("v_med3_u32 %0, %1, %2, %3" : "=v"(d) : "v"(a), "v"(b), "v"(c));
    return d;
}
__device__ __forceinline__ int cell1(float v) {
    int c = (int)floorf((v - LOF) * INVW);
    return min(max(c, 0), G - 1);
}
__device__ __forceinline__ unsigned spread3(unsigned v) {  // 4-bit -> bits 0,3,6,9
    return (v & 1u) | ((v & 2u) << 2) | ((v & 4u) << 4) | ((v & 8u) << 6);
}

// ---------------- Morton-sort query indices (one block per batch) ----------
__global__ __launch_bounds__(1024)
void k_qsort(const float* __restrict__ xyz, unsigned* __restrict__ dsrt)
{
    __shared__ unsigned pk[2048];          // packed u16 counts -> cursors
    __shared__ unsigned wsum[16];
    const int b = blockIdx.x;
    const int t = threadIdx.x;
    const float* xb = xyz + (size_t)b * 3 * NQ;

    pk[t] = 0u; pk[t + 1024] = 0u;
    __syncthreads();

    unsigned short mc[16];
    #pragma unroll
    for (int k = 0; k < 16; ++k) {                 // histogram (coalesced reads)
        const int q = k * 1024 + t;
        const int hx = cell1(xb[q]), hy = cell1(xb[NQ + q]), hz = cell1(xb[2 * NQ + q]);
        const unsigned m = spread3(hx) | (spread3(hy) << 1) | (spread3(hz) << 2);
        mc[k] = (unsigned short)m;
        atomicAdd(&pk[m >> 1], (m & 1) ? 0x10000u : 1u);
    }
    __syncthreads();

    {   // exclusive scan of 4096 u16 counts (thread t owns cells 4t..4t+3)
        const unsigned w0 = pk[2 * t], w1 = pk[2 * t + 1];
        const unsigned c0 = w0 & 0xFFFFu, c1 = w0 >> 16;
        const unsigned c2 = w1 & 0xFFFFu, c3 = w1 >> 16;
        const unsigned tsum = c0 + c1 + c2 + c3;
        const int lane = t & 63, w = t >> 6;
        unsigned sc = tsum;
        #pragma unroll
        for (int d = 1; d < 64; d <<= 1) {
            const unsigned o = __shfl_up(sc, d, 64);
            if (lane >= d) sc += o;
        }
        if (lane == 63) wsum[w] = sc;
        __syncthreads();
        unsigned wbase = 0;
        #pragma unroll
        for (int k = 0; k < 16; ++k) wbase += (k < w) ? wsum[k] : 0u;
        unsigned e = wbase + sc - tsum;
        const unsigned e0 = e; e += c0;
        const unsigned e1 = e; e += c1;
        const unsigned e2 = e; e += c2;
        const unsigned e3 = e;
        __syncthreads();                           // all reads of pk done
        pk[2 * t]     = e0 | (e1 << 16);
        pk[2 * t + 1] = e2 | (e3 << 16);
    }
    __syncthreads();

    #pragma unroll
    for (int k = 0; k < 16; ++k) {                 // scatter sorted indices
        const int q = k * 1024 + t;
        const unsigned m = mc[k];
        const unsigned old = atomicAdd(&pk[m >> 1], (m & 1) ? 0x10000u : 1u);
        const unsigned pos = (m & 1) ? (old >> 16) : (old & 0xFFFFu);
        dsrt[b * NQ + pos] = (unsigned)q;
    }
}

// ---------------- main: build + wave-uniform culled scan + epilogue --------
__global__ __launch_bounds__(THREADS)
void k_knn(const float* __restrict__ xyz, const float* __restrict__ sxyz,
           const float* __restrict__ sflow, float* __restrict__ out,
           const unsigned* __restrict__ dsrt)
{
    __shared__ float px[S], py[S], pz[S];            // 48 KiB cell-sorted coords
    __shared__ unsigned short pfx16[NC + 1];         // cell prefix table
    __shared__ unsigned short sidx[S];               // sorted -> orig index
    __shared__ unsigned scratch[2048];               // build cnt/cursors (packed)
    __shared__ unsigned wtot[4];

    const int t   = threadIdx.x;
    const int blk = blockIdx.x;                      // 0..255
    const int b   = blk >> 7;
    const int chk = blk & 127;

    // ========== build sparse grid in LDS (verbatim round 7, proven) ========
    const float* sxb = sxyz + (size_t)b * 3 * S;
    float xx[PPT], yy[PPT], zz[PPT];
    {
        const float4* vx = reinterpret_cast<const float4*>(sxb + t * PPT);
        const float4* vy = reinterpret_cast<const float4*>(sxb + S + t * PPT);
        const float4* vz = reinterpret_cast<const float4*>(sxb + 2 * S + t * PPT);
        #pragma unroll
        for (int k = 0; k < PPT / 4; ++k) {
            const float4 a = vx[k], c = vy[k], d = vz[k];
            xx[4*k+0]=a.x; xx[4*k+1]=a.y; xx[4*k+2]=a.z; xx[4*k+3]=a.w;
            yy[4*k+0]=c.x; yy[4*k+1]=c.y; yy[4*k+2]=c.z; yy[4*k+3]=c.w;
            zz[4*k+0]=d.x; zz[4*k+1]=d.y; zz[4*k+2]=d.z; zz[4*k+3]=d.w;
        }
    }
    #pragma unroll
    for (int k = 0; k < 8; ++k) scratch[t * 8 + k] = 0u;
    __syncthreads();

    #pragma unroll
    for (int k = 0; k < PPT; ++k) {
        const int ci = (cell1(zz[k]) * G + cell1(yy[k])) * G + cell1(xx[k]);
        atomicAdd(&scratch[ci >> 1], (ci & 1) ? 0x10000u : 1u);
    }
    __syncthreads();

    {
        unsigned c[16];
        #pragma unroll
        for (int k = 0; k < 8; ++k) {
            const unsigned w2 = scratch[t * 8 + k];
            c[2*k] = w2 & 0xFFFFu; c[2*k+1] = w2 >> 16;
        }
        unsigned tsum = 0;
        #pragma unroll
        for (int k = 0; k < 16; ++k) { const unsigned v = c[k]; c[k] = tsum; tsum += v; }
        const int lane = t & 63, w = t >> 6;
        unsigned sc = tsum;
        #pragma unroll
        for (int d = 1; d < 64; d <<= 1) {
            const unsigned o = __shfl_up(sc, d, 64);
            if (lane >= d) sc += o;
        }
        if (lane == 63) wtot[w] = sc;
        __syncthreads();
        unsigned wbase = 0;
        #pragma unroll
        for (int k = 0; k < 4; ++k) wbase += (k < w) ? wtot[k] : 0u;
        const unsigned base = wbase + sc - tsum;
        #pragma unroll
        for (int k = 0; k < 16; ++k) pfx16[t * 16 + k] = (unsigned short)(base + c[k]);
        #pragma unroll
        for (int k = 0; k < 8; ++k)
            scratch[t * 8 + k] = (base + c[2*k]) | ((base + c[2*k+1]) << 16);
        if (t == 0) pfx16[NC] = (unsigned short)S;
    }
    __syncthreads();

    #pragma unroll
    for (int k = 0; k < PPT; ++k) {
        const int ci = (cell1(zz[k]) * G + cell1(yy[k])) * G + cell1(xx[k]);
        const unsigned old = atomicAdd(&scratch[ci >> 1], (ci & 1) ? 0x10000u : 1u);
        const unsigned pos = (ci & 1) ? (old >> 16) : (old & 0xFFFFu);
        px[pos] = xx[k]; py[pos] = yy[k]; pz[pos] = zz[k];
        sidx[pos] = (unsigned short)(t * PPT + k);
    }
    __syncthreads();

    // ========== wave-autonomous query phase (no more barriers) =============
    const int lane  = t & 63;
    const int wv    = t >> 6;
    const int qslot = chk * QPB + wv * QPW + (lane >> 1);
    const unsigned qi = dsrt[b * NQ + qslot];

    const float* xb = xyz + (size_t)b * 3 * NQ;
    const float qx = xb[qi], qy = xb[NQ + qi], qz = xb[2 * NQ + qi];
    const int hx = cell1(qx), hy = cell1(qy), hz = cell1(qz);

    // wave bbox of home cells (shfl butterfly reduce)
    int bx0 = hx, bx1 = hx, by0 = hy, by1 = hy, bz0 = hz, bz1 = hz;
    #pragma unroll
    for (int d = 1; d < 64; d <<= 1) {
        bx0 = min(bx0, __shfl_xor(bx0, d, 64)); bx1 = max(bx1, __shfl_xor(bx1, d, 64));
        by0 = min(by0, __shfl_xor(by0, d, 64)); by1 = max(by1, __shfl_xor(by1, d, 64));
        bz0 = min(bz0, __shfl_xor(bz0, d, 64)); bz1 = max(bz1, __shfl_xor(bz1, d, 64));
    }

    // df: query's min distance to the box faces (>=0 inside; clamp at use)
    float df;
    {
        const float gx0 = LOF + bx0 * W, gx1 = LOF + (bx1 + 1) * W;
        const float gy0 = LOF + by0 * W, gy1 = LOF + (by1 + 1) * W;
        const float gz0 = LOF + bz0 * W, gz1 = LOF + (bz1 + 1) * W;
        df = fminf(fminf(fminf(qx - gx0, gx1 - qx), fminf(qy - gy0, gy1 - qy)),
                   fminf(qz - gz0, gz1 - qz));
    }

    unsigned kk0 = 0xFFFFFFFFu, kk1 = 0xFFFFFFFFu,
             kk2 = 0xFFFFFFFFu, kk3 = 0xFFFFFFFFu;
    const int par = t & 1;                            // pair split: even/odd pts

    auto probe = [&](int ci0, int ci1) {              // wave-uniform segment
        const unsigned s0 = pfx16[ci0];
        const unsigned e0 = pfx16[ci1];
        for (unsigned j = s0 + par; j < e0; j += 2) {
            const float ddx = qx - px[j];
            const float ddy = qy - py[j];
            const float ddz = qz - pz[j];
            const float d2 = ddx*ddx + ddy*ddy + ddz*ddz;
            const unsigned c = (__float_as_uint(d2) & 0xFFFFF000u) | j;
            kk3 = med3u(kk2, kk3, c);
            kk2 = med3u(kk1, kk2, c);
            kk1 = med3u(kk0, kk1, c);
            kk0 = min(kk0, c);
        }
    };

    for (int r = 0; r <= G; ++r) {
        const int z0 = max(bz0 - r, 0), z1 = min(bz1 + r, G - 1);
        const int y0 = max(by0 - r, 0), y1 = min(by1 + r, G - 1);
        for (int z = z0; z <= z1; ++z) {
            const bool zb = (z == bz0 - r) || (z == bz1 + r);
            for (int y = y0; y <= y1; ++y) {
                const int rowb = (z * G + y) * G;
                const bool full = (r == 0) || zb || (y == by0 - r) || (y == by1 + r);
                if (full) {
                    const int x0 = max(bx0 - r, 0), x1 = min(bx1 + r, G - 1);
                    probe(rowb + x0, rowb + x1 + 1);
                } else {
                    const int xl = bx0 - r, xr = bx1 + r;
                    if (xl >= 0)  probe(rowb + xl, rowb + xl + 1);
                    if (xr < G)   probe(rowb + xr, rowb + xr + 1);
                }
            }
        }
        // full coverage -> everything scanned
        if (bz0 - r <= 0 && bz1 + r >= G - 1 && by0 - r <= 0 && by1 + r >= G - 1 &&
            bx0 - r <= 0 && bx1 + r >= G - 1) break;
        // termination: unscanned cells are > r*W + df from this query
        unsigned d3u = min(kk2, (unsigned)__shfl_xor((int)kk2, 1, 64));
        const float d3f = __uint_as_float(d3u | 0xFFFu) * 1.0001f;  // NaN if <3
        const float lb  = (float)r * W + fmaxf(df, 0.0f);
        if (__all(lb * lb > d3f)) break;
    }

    // pair merge: partner's 4 keys via shfl (unconditional, then even lane acts)
    const unsigned o0 = (unsigned)__shfl_xor((int)kk0, 1, 64);
    const unsigned o1 = (unsigned)__shfl_xor((int)kk1, 1, 64);
    const unsigned o2 = (unsigned)__shfl_xor((int)kk2, 1, 64);
    const unsigned o3 = (unsigned)__shfl_xor((int)kk3, 1, 64);

    if (par == 0) {
        const unsigned bkarr[8] = { kk0, kk1, kk2, kk3, o0, o1, o2, o3 };
        const double qxd = (double)qx, qyd = (double)qy, qzd = (double)qz;
        double e0 = 1e300, e1 = 1e300, e2 = 1e300;
        int    i0 = 0,     i1 = 0,     i2 = 0;
        #pragma unroll
        for (int c = 0; c < 8; ++c) {
            const unsigned key = bkarr[c];
            if (key == 0xFFFFFFFFu) continue;
            const int j = (int)(key & 0xFFFu);
            const double dx = qxd - (double)px[j];
            const double dy = qyd - (double)py[j];
            const double dz = qzd - (double)pz[j];
            const double d2 = dx * dx + dy * dy + dz * dz;
            if (d2 < e2) {
                if (d2 < e1) {
                    e2 = e1; i2 = i1;
                    if (d2 < e0) { e1 = e0; i1 = i0; e0 = d2; i0 = j; }
                    else         { e1 = d2; i1 = j; }
                } else {
                    e2 = d2; i2 = j;
                }
            }
        }

        double dist0 = sqrt(e0); dist0 = dist0 > 1e-10 ? dist0 : 1e-10;
        double dist1 = sqrt(e1); dist1 = dist1 > 1e-10 ? dist1 : 1e-10;
        double dist2 = sqrt(e2); dist2 = dist2 > 1e-10 ? dist2 : 1e-10;
        const double inv0 = 1.0 / dist0;
        const double inv1 = 1.0 / dist1;
        const double inv2 = 1.0 / dist2;
        const double wsum = inv0 + inv1 + inv2;

        const int so0 = sidx[i0], so1 = sidx[i1], so2 = sidx[i2];
        const float* fb = sflow + (size_t)b * 3 * S;
        float*       ob = out   + (size_t)b * 3 * NQ;
        #pragma unroll
        for (int c = 0; c < 3; ++c) {
            const float* fc = fb + c * S;
            const double o =
                (inv0 * (double)fc[so0] +
                 inv1 * (double)fc[so1] +
                 inv2 * (double)fc[so2]) / wsum;
            ob[c * NQ + qi] = (float)o;
        }
    }
}

extern "C" void kernel_launch(void* const* d_in, const int* in_sizes, int n_in,
                              void* d_out, int out_size, void* d_ws, size_t ws_size,
                              hipStream_t stream)
{
    const float* xyz  = (const float*)d_in[0];
    const float* sxyz = (const float*)d_in[1];
    const float* sflw = (const float*)d_in[2];
    float*       out  = (float*)d_out;
    unsigned*    dsrt = (unsigned*)d_ws;        // u32[2][16384] = 128 KB

    k_qsort<<<B, 1024, 0, stream>>>(xyz, dsrt);

    const int blocks = (B * NQ) / QPB;          // 256 (1 per CU)
    k_knn<<<blocks, THREADS, 0, stream>>>(xyz, sxyz, sflw, out, dsrt);
}

// Round 10
// 221.931 us; speedup vs baseline: 1.2521x; 1.2521x over previous
//
#include <hip/hip_runtime.h>

// 3-NN IDW upsampling, round 10: round 9 + top-4 keys per lane (fixes the
// round-9 correctness failure: top-3/lane had zero slack against 2^-11
// key-truncation ties, which could drop the true 3rd neighbor from the
// candidate set; top-4/lane needs two same-lane ties, strictly safer than
// the round-8 configuration that passed).
// k_qsort: Morton-sort query indices (byte-identical to rounds 8/9).
// k_knn: 256 blocks x 512 thr; per-block LDS sparse grid build; each wave
//   serves 16 queries (4 lanes/query). Two-shot scan: box+-1 -> d3 upper
//   bound -> r = ceil((sqrt(d3ub)-df)/W); if wave-max r <= 1 done, else one
//   rescan of box+-r. Segment bounds fetched wave-parallel, shfl-broadcast.
//   4 packed keys/lane -> 16 candidates/query -> exact-f64 re-rank + f64 IDW
//   (identical epilogue arithmetic to rounds 1-8; absmax 0.00390625).

constexpr int   B  = 2;
constexpr int   S  = 4096;
constexpr int   NQ = 16384;
constexpr int   G  = 16;
constexpr int   NC = G * G * G;
constexpr float LOF  = -4.25f;
constexpr float W    = 0.53125f;          // 8.5 / 16
constexpr float INVW = 1.0f / W;

constexpr int THREADS = 512;              // 8 waves
constexpr int PPT     = S / THREADS;      // 8 sparse points per thread (build)
constexpr int QPW     = 16;               // queries per wave (4 lanes each)
constexpr int QPB     = 8 * QPW;          // 128 queries per block

__device__ __forceinline__ unsigned med3u(unsigned a, unsigned b, unsigned c) {
    unsigned d;
    asm("v_med3_u32 %0, %1, %2, %3" : "=v"(d) : "v"(a), "v"(b), "v"(c));
    return d;
}
__device__ __forceinline__ int cell1(float v) {
    int c = (int)floorf((v - LOF) * INVW);
    return min(max(c, 0), G - 1);
}
__device__ __forceinline__ unsigned spread3(unsigned v) {  // 4-bit -> bits 0,3,6,9
    return (v & 1u) | ((v & 2u) << 2) | ((v & 4u) << 4) | ((v & 8u) << 6);
}

// ---------------- Morton-sort query indices (one block per batch) ----------
__global__ __launch_bounds__(1024)
void k_qsort(const float* __restrict__ xyz, unsigned* __restrict__ dsrt)
{
    __shared__ unsigned pk[2048];
    __shared__ unsigned wsum[16];
    const int b = blockIdx.x;
    const int t = threadIdx.x;
    const float* xb = xyz + (size_t)b * 3 * NQ;

    pk[t] = 0u; pk[t + 1024] = 0u;
    __syncthreads();

    unsigned short mc[16];
    #pragma unroll
    for (int k = 0; k < 16; ++k) {
        const int q = k * 1024 + t;
        const int hx = cell1(xb[q]), hy = cell1(xb[NQ + q]), hz = cell1(xb[2 * NQ + q]);
        const unsigned m = spread3(hx) | (spread3(hy) << 1) | (spread3(hz) << 2);
        mc[k] = (unsigned short)m;
        atomicAdd(&pk[m >> 1], (m & 1) ? 0x10000u : 1u);
    }
    __syncthreads();

    {
        const unsigned w0 = pk[2 * t], w1 = pk[2 * t + 1];
        const unsigned c0 = w0 & 0xFFFFu, c1 = w0 >> 16;
        const unsigned c2 = w1 & 0xFFFFu, c3 = w1 >> 16;
        const unsigned tsum = c0 + c1 + c2 + c3;
        const int lane = t & 63, w = t >> 6;
        unsigned sc = tsum;
        #pragma unroll
        for (int d = 1; d < 64; d <<= 1) {
            const unsigned o = __shfl_up(sc, d, 64);
            if (lane >= d) sc += o;
        }
        if (lane == 63) wsum[w] = sc;
        __syncthreads();
        unsigned wbase = 0;
        #pragma unroll
        for (int k = 0; k < 16; ++k) wbase += (k < w) ? wsum[k] : 0u;
        unsigned e = wbase + sc - tsum;
        const unsigned e0 = e; e += c0;
        const unsigned e1 = e; e += c1;
        const unsigned e2 = e; e += c2;
        const unsigned e3 = e;
        __syncthreads();
        pk[2 * t]     = e0 | (e1 << 16);
        pk[2 * t + 1] = e2 | (e3 << 16);
    }
    __syncthreads();

    #pragma unroll
    for (int k = 0; k < 16; ++k) {
        const int q = k * 1024 + t;
        const unsigned m = mc[k];
        const unsigned old = atomicAdd(&pk[m >> 1], (m & 1) ? 0x10000u : 1u);
        const unsigned pos = (m & 1) ? (old >> 16) : (old & 0xFFFFu);
        dsrt[b * NQ + pos] = (unsigned)q;
    }
}

// ---------------- main: build + two-shot culled scan + epilogue ------------
__global__ __launch_bounds__(THREADS, 2)
void k_knn(const float* __restrict__ xyz, const float* __restrict__ sxyz,
           const float* __restrict__ sflow, float* __restrict__ out,
           const unsigned* __restrict__ dsrt)
{
    __shared__ float px[S], py[S], pz[S];            // 48 KiB cell-sorted coords
    __shared__ unsigned short pfx16[NC + 1];         // cell prefix table
    __shared__ unsigned short sidx[S];               // sorted -> orig index
    __shared__ unsigned scratch[2048];               // build cnt/cursors (packed)
    __shared__ unsigned wtot[8];

    const int t   = threadIdx.x;
    const int blk = blockIdx.x;                      // 0..255
    const int b   = blk >> 7;
    const int chk = blk & 127;

    // ========== build sparse grid in LDS =====================================
    const float* sxb = sxyz + (size_t)b * 3 * S;
    float xx[PPT], yy[PPT], zz[PPT];
    {
        const float4* vx = reinterpret_cast<const float4*>(sxb + t * PPT);
        const float4* vy = reinterpret_cast<const float4*>(sxb + S + t * PPT);
        const float4* vz = reinterpret_cast<const float4*>(sxb + 2 * S + t * PPT);
        #pragma unroll
        for (int k = 0; k < PPT / 4; ++k) {
            const float4 a = vx[k], c = vy[k], d = vz[k];
            xx[4*k+0]=a.x; xx[4*k+1]=a.y; xx[4*k+2]=a.z; xx[4*k+3]=a.w;
            yy[4*k+0]=c.x; yy[4*k+1]=c.y; yy[4*k+2]=c.z; yy[4*k+3]=c.w;
            zz[4*k+0]=d.x; zz[4*k+1]=d.y; zz[4*k+2]=d.z; zz[4*k+3]=d.w;
        }
    }
    #pragma unroll
    for (int k = 0; k < 4; ++k) scratch[t * 4 + k] = 0u;
    __syncthreads();

    #pragma unroll
    for (int k = 0; k < PPT; ++k) {
        const int ci = (cell1(zz[k]) * G + cell1(yy[k])) * G + cell1(xx[k]);
        atomicAdd(&scratch[ci >> 1], (ci & 1) ? 0x10000u : 1u);
    }
    __syncthreads();

    {   // exclusive scan of 4096 u16 counts (thread t owns cells 8t..8t+7)
        unsigned c[8];
        #pragma unroll
        for (int k = 0; k < 4; ++k) {
            const unsigned w2 = scratch[t * 4 + k];
            c[2*k] = w2 & 0xFFFFu; c[2*k+1] = w2 >> 16;
        }
        unsigned tsum = 0;
        #pragma unroll
        for (int k = 0; k < 8; ++k) { const unsigned v = c[k]; c[k] = tsum; tsum += v; }
        const int lane = t & 63, w = t >> 6;
        unsigned sc = tsum;
        #pragma unroll
        for (int d = 1; d < 64; d <<= 1) {
            const unsigned o = __shfl_up(sc, d, 64);
            if (lane >= d) sc += o;
        }
        if (lane == 63) wtot[w] = sc;
        __syncthreads();
        unsigned wbase = 0;
        #pragma unroll
        for (int k = 0; k < 8; ++k) wbase += (k < w) ? wtot[k] : 0u;
        const unsigned base = wbase + sc - tsum;
        #pragma unroll
        for (int k = 0; k < 8; ++k) pfx16[t * 8 + k] = (unsigned short)(base + c[k]);
        #pragma unroll
        for (int k = 0; k < 4; ++k)
            scratch[t * 4 + k] = (base + c[2*k]) | ((base + c[2*k+1]) << 16);
        if (t == 0) pfx16[NC] = (unsigned short)S;
    }
    __syncthreads();

    #pragma unroll
    for (int k = 0; k < PPT; ++k) {
        const int ci = (cell1(zz[k]) * G + cell1(yy[k])) * G + cell1(xx[k]);
        const unsigned old = atomicAdd(&scratch[ci >> 1], (ci & 1) ? 0x10000u : 1u);
        const unsigned pos = (ci & 1) ? (old >> 16) : (old & 0xFFFFu);
        px[pos] = xx[k]; py[pos] = yy[k]; pz[pos] = zz[k];
        sidx[pos] = (unsigned short)(t * PPT + k);
    }
    __syncthreads();

    // ========== wave-autonomous query phase ================================
    const int lane  = t & 63;
    const int wv    = t >> 6;
    const int par   = lane & 3;                      // quad split: j mod 4
    const int qslot = chk * QPB + wv * QPW + (lane >> 2);
    const unsigned qi = dsrt[b * NQ + qslot];

    const float* xb = xyz + (size_t)b * 3 * NQ;
    const float qx = xb[qi], qy = xb[NQ + qi], qz = xb[2 * NQ + qi];
    const int hx = cell1(qx), hy = cell1(qy), hz = cell1(qz);

    // wave bbox of home cells
    int bx0 = hx, bx1 = hx, by0 = hy, by1 = hy, bz0 = hz, bz1 = hz;
    #pragma unroll
    for (int d = 1; d < 64; d <<= 1) {
        bx0 = min(bx0, __shfl_xor(bx0, d, 64)); bx1 = max(bx1, __shfl_xor(bx1, d, 64));
        by0 = min(by0, __shfl_xor(by0, d, 64)); by1 = max(by1, __shfl_xor(by1, d, 64));
        bz0 = min(bz0, __shfl_xor(bz0, d, 64)); bz1 = max(bz1, __shfl_xor(bz1, d, 64));
    }

    // signed distance from q to the box boundary (positive inside, negative
    // outside). Any point outside box+-r is >= r*W + df away. NOT clamped.
    float df;
    {
        const float gx0 = LOF + bx0 * W, gx1 = LOF + (bx1 + 1) * W;
        const float gy0 = LOF + by0 * W, gy1 = LOF + (by1 + 1) * W;
        const float gz0 = LOF + bz0 * W, gz1 = LOF + (bz1 + 1) * W;
        df = fminf(fminf(fminf(qx - gx0, gx1 - qx), fminf(qy - gy0, gy1 - qy)),
                   fminf(qz - gz0, gz1 - qz));
    }

    unsigned kk0, kk1, kk2, kk3;

    // wave-uniform region scan; bounds fetched lane-parallel per z-slab
    auto scan = [&](int x0, int x1, int y0, int y1, int z0, int z1) {
        kk0 = kk1 = kk2 = kk3 = 0xFFFFFFFFu;
        const int ny = y1 - y0 + 1;                  // <= 16 <= 64 lanes
        for (int z = z0; z <= z1; ++z) {
            unsigned ss = 0, se = 0;
            if (lane < ny) {                          // parallel bounds fetch
                const int rb = (z * G + (y0 + lane)) * G;
                ss = pfx16[rb + x0];
                se = pfx16[rb + x1 + 1];
            }
            for (int yy = 0; yy < ny; ++yy) {
                const unsigned s0 = (unsigned)__shfl((int)ss, yy, 64);
                const unsigned e0 = (unsigned)__shfl((int)se, yy, 64);
                for (unsigned j = s0 + par; j < e0; j += 4) {
                    const float ddx = qx - px[j];
                    const float ddy = qy - py[j];
                    const float ddz = qz - pz[j];
                    const float d2 = ddx*ddx + ddy*ddy + ddz*ddz;
                    const unsigned c = (__float_as_uint(d2) & 0xFFFFF000u) | j;
                    kk3 = med3u(kk2, kk3, c);
                    kk2 = med3u(kk1, kk2, c);
                    kk1 = med3u(kk0, kk1, c);
                    kk0 = min(kk0, c);
                }
            }
        }
    };

    // ---- shot 1: box +- 1 ----
    scan(max(bx0 - 1, 0), min(bx1 + 1, G - 1),
         max(by0 - 1, 0), min(by1 + 1, G - 1),
         max(bz0 - 1, 0), min(bz1 + 1, G - 1));

    // quad d3 upper bound: min over 4 lanes of (3rd-best key of lane subset)
    unsigned d3u = kk2;
    d3u = min(d3u, (unsigned)__shfl_xor((int)d3u, 1, 64));
    d3u = min(d3u, (unsigned)__shfl_xor((int)d3u, 2, 64));

    int rq;
    if (d3u == 0xFFFFFFFFu) {
        rq = G;                                      // <3 candidates: full scan
    } else {
        const float d3f = __uint_as_float(d3u | 0xFFFu) * 1.0002f;  // round up
        rq = (int)ceilf((sqrtf(d3f) - df) * INVW + 1e-4f);
        rq = min(max(rq, 0), G);
    }
    int rw = rq;                                     // wave max
    #pragma unroll
    for (int d = 1; d < 64; d <<= 1) rw = max(rw, __shfl_xor(rw, d, 64));

    // ---- shot 2 (only if box+-1 doesn't cover): rescan box +- rw ----
    if (rw > 1) {
        scan(max(bx0 - rw, 0), min(bx1 + rw, G - 1),
             max(by0 - rw, 0), min(by1 + rw, G - 1),
             max(bz0 - rw, 0), min(bz1 + rw, G - 1));
    }

    // gather the quad's 16 candidate keys onto every lane
    const unsigned a0 = kk0, a1 = kk1, a2 = kk2, a3 = kk3;
    const unsigned q0 = (unsigned)__shfl_xor((int)a0, 1, 64);
    const unsigned q1 = (unsigned)__shfl_xor((int)a1, 1, 64);
    const unsigned q2 = (unsigned)__shfl_xor((int)a2, 1, 64);
    const unsigned q3 = (unsigned)__shfl_xor((int)a3, 1, 64);
    const unsigned r0 = (unsigned)__shfl_xor((int)a0, 2, 64);
    const unsigned r1 = (unsigned)__shfl_xor((int)a1, 2, 64);
    const unsigned r2 = (unsigned)__shfl_xor((int)a2, 2, 64);
    const unsigned r3 = (unsigned)__shfl_xor((int)a3, 2, 64);
    const unsigned s0k = (unsigned)__shfl_xor((int)q0, 2, 64);
    const unsigned s1k = (unsigned)__shfl_xor((int)q1, 2, 64);
    const unsigned s2k = (unsigned)__shfl_xor((int)q2, 2, 64);
    const unsigned s3k = (unsigned)__shfl_xor((int)q3, 2, 64);

    if (par == 0) {
        const unsigned bkarr[16] = { a0, a1, a2, a3, q0, q1, q2, q3,
                                     r0, r1, r2, r3, s0k, s1k, s2k, s3k };
        const double qxd = (double)qx, qyd = (double)qy, qzd = (double)qz;
        double e0 = 1e300, e1 = 1e300, e2 = 1e300;
        int    i0 = 0,     i1 = 0,     i2 = 0;
        #pragma unroll
        for (int c = 0; c < 16; ++c) {
            const unsigned key = bkarr[c];
            if (key == 0xFFFFFFFFu) continue;
            const int j = (int)(key & 0xFFFu);
            const double dx = qxd - (double)px[j];
            const double dy = qyd - (double)py[j];
            const double dz = qzd - (double)pz[j];
            const double d2 = dx * dx + dy * dy + dz * dz;
            if (d2 < e2) {
                if (d2 < e1) {
                    e2 = e1; i2 = i1;
                    if (d2 < e0) { e1 = e0; i1 = i0; e0 = d2; i0 = j; }
                    else         { e1 = d2; i1 = j; }
                } else {
                    e2 = d2; i2 = j;
                }
            }
        }

        double dist0 = sqrt(e0); dist0 = dist0 > 1e-10 ? dist0 : 1e-10;
        double dist1 = sqrt(e1); dist1 = dist1 > 1e-10 ? dist1 : 1e-10;
        double dist2 = sqrt(e2); dist2 = dist2 > 1e-10 ? dist2 : 1e-10;
        const double inv0 = 1.0 / dist0;
        const double inv1 = 1.0 / dist1;
        const double inv2 = 1.0 / dist2;
        const double wsum = inv0 + inv1 + inv2;

        const int so0 = sidx[i0], so1 = sidx[i1], so2 = sidx[i2];
        const float* fb = sflow + (size_t)b * 3 * S;
        float*       ob = out   + (size_t)b * 3 * NQ;
        #pragma unroll
        for (int c = 0; c < 3; ++c) {
            const float* fc = fb + c * S;
            const double o =
                (inv0 * (double)fc[so0] +
                 inv1 * (double)fc[so1] +
                 inv2 * (double)fc[so2]) / wsum;
            ob[c * NQ + qi] = (float)o;
        }
    }
}

extern "C" void kernel_launch(void* const* d_in, const int* in_sizes, int n_in,
                              void* d_out, int out_size, void* d_ws, size_t ws_size,
                              hipStream_t stream)
{
    const float* xyz  = (const float*)d_in[0];
    const float* sxyz = (const float*)d_in[1];
    const float* sflw = (const float*)d_in[2];
    float*       out  = (float*)d_out;
    unsigned*    dsrt = (unsigned*)d_ws;        // u32[2][16384] = 128 KB

    k_qsort<<<B, 1024, 0, stream>>>(xyz, dsrt);

    const int blocks = (B * NQ) / QPB;          // 256 blocks x 512 thr
    k_knn<<<blocks, THREADS, 0, stream>>>(xyz, sxyz, sflw, out, dsrt);
}